// Round 3
// baseline (45643.909 us; speedup 1.0000x reference)
//
#include <hip/hip_runtime.h>

typedef __attribute__((ext_vector_type(8))) short short8;
typedef __attribute__((ext_vector_type(4))) float floatx4;
typedef unsigned short ushort_t;

#define NB 256
#define NT 512
constexpr int B_ = 64, T_ = 512, D_ = 1024, H_ = 1024, O_ = 256;
constexpr size_t WELEM = (size_t)4 * 4096 * 1024;   // elements per weight tensor (L*4H*K)

// ---- ws layout (bytes) ----
constexpr size_t WS_BAR   = 0;          // 2KB barrier (gen at +16 words, slots at +32 words)
constexpr size_t WS_MODE  = 4096;       // unsigned dtype flag: 1 = f32 inputs
constexpr size_t WS_HBUF  = 8192;                          // bf16 [4][2][B][H] = 1 MiB
constexpr size_t WS_HLAST = WS_HBUF + (size_t)4*2*B_*H_*2; // f32 [B][H] = 256 KiB
constexpr size_t WS_WIH   = 1572864;                       // bf16 Wih, 32 MiB
constexpr size_t WS_WHH   = WS_WIH + WELEM*2;              // bf16 Whh, 32 MiB
constexpr size_t WS_NEED  = WS_WHH + WELEM*2;              // ~68.7 MB

__device__ __forceinline__ float bs2f(ushort_t s){
  union { unsigned u; float f; } v; v.u = ((unsigned)s) << 16; return v.f;
}
__device__ __forceinline__ ushort_t f2bs(float f){
  union { float f; unsigned u; } v; v.f = f;
  unsigned r = (v.u + 0x7fffu + ((v.u >> 16) & 1u)) >> 16;
  return (ushort_t)r;
}
__device__ __forceinline__ float sigf(float x){ return 1.f/(1.f + __expf(-x)); }
__device__ __forceinline__ float tanh_f(float x){ return 1.f - 2.f/(__expf(2.f*x) + 1.f); }
__device__ __forceinline__ short8 ldb8(const ushort_t* p){ return *(const short8*)p; }
__device__ __forceinline__ short8 cvt8(const float* p){
  short8 r;
  #pragma unroll
  for (int j = 0; j < 8; ++j) r[j] = (short)f2bs(p[j]);
  return r;
}

// ---- kernel 1: dtype sniff + barrier init ----
// bf16 data: every ushort is a bf16 of |v|<~1 -> exponent <= ~0x82.
// f32 data read as ushorts: even words are mantissa halves -> ~46% have exp >= 0x89.
__global__ void sniff_init(const ushort_t* __restrict__ fcb_u,
                           unsigned* __restrict__ bar, unsigned* __restrict__ mode){
  __shared__ int cnt;
  if (threadIdx.x == 0) cnt = 0;
  __syncthreads();
  unsigned* slots = bar + 32;
  if (threadIdx.x < NB) slots[threadIdx.x] = 0u;
  if (threadIdx.x == 0) bar[16] = 0u;   // gen
  unsigned u = fcb_u[threadIdx.x];      // first 512B of fcb: safe for both dtypes
  unsigned e = (u >> 7) & 0xFFu;
  if (e >= 0x89u) atomicAdd(&cnt, 1);
  __syncthreads();
  if (threadIdx.x == 0) *mode = (cnt >= 4) ? 1u : 0u;
}

// ---- kernel 2: weight f32 -> bf16 (RNE) into ws; no-op in bf16 mode ----
__global__ void wconv(const float* __restrict__ WihF, const float* __restrict__ WhhF,
                      ushort_t* __restrict__ oWih, ushort_t* __restrict__ oWhh,
                      const unsigned* __restrict__ mode, int ws_ok){
  if (*mode != 1u || !ws_ok) return;
  size_t stride = (size_t)gridDim.x * blockDim.x;
  for (size_t i = (size_t)blockIdx.x*blockDim.x + threadIdx.x; i < WELEM; i += stride){
    oWih[i] = f2bs(WihF[i]);
    oWhh[i] = f2bs(WhhF[i]);
  }
}

// ---- kernel 3: pipelined persistent LSTM (r2 structure) ----
__global__ __launch_bounds__(NT, 2)
void lstm_pipe(const void* __restrict__ xv,   const void* __restrict__ Wihv,
               const void* __restrict__ Whhv, const void* __restrict__ bihv,
               const void* __restrict__ bhhv, const void* __restrict__ fcwv,
               const void* __restrict__ fcbv, void* __restrict__ outv,
               ushort_t* __restrict__ hbuf, float* __restrict__ hlast,
               unsigned* __restrict__ bar, const unsigned* __restrict__ modep,
               const ushort_t* __restrict__ wsWih, const ushort_t* __restrict__ wsWhh,
               int ws_ok)
{
  const int tid  = threadIdx.x;
  const int bx   = blockIdx.x;
  const int lane = tid & 63;
  const int wv   = tid >> 6;
  const int q    = lane >> 4;
  const int l15  = lane & 15;
  const int wg   = wv >> 1;          // gate
  const int mh   = wv & 1;           // m-half
  const int layer = bx >> 6;
  const int jbase = (bx & 63) * 16;

  __shared__ float xch[4][64][17];

  const unsigned md = *modep;
  const bool f32in  = (md == 1u);
  const bool rawf32 = f32in && !ws_ok;

  const ushort_t* wihB = f32in ? wsWih : (const ushort_t*)Wihv;
  const ushort_t* whhB = f32in ? wsWhh : (const ushort_t*)Whhv;
  const float*    wihF = (const float*)Wihv;
  const float*    whhF = (const float*)Whhv;
  const float*    xF   = (const float*)xv;
  const ushort_t* xB   = (const ushort_t*)xv;

  unsigned* gen   = bar + 16;
  unsigned* slots = bar + 32;
  unsigned bgen = 0;
  auto gridbar = [&](){
    __syncthreads();
    bgen += 1;
    if (bx == 0){
      for (int i = 1 + tid; i < NB; i += NT){
        while (__hip_atomic_load(&slots[i], __ATOMIC_ACQUIRE, __HIP_MEMORY_SCOPE_AGENT) < bgen)
          __builtin_amdgcn_s_sleep(1);
      }
      __syncthreads();
      if (tid == 0)
        __hip_atomic_store(gen, bgen, __ATOMIC_RELEASE, __HIP_MEMORY_SCOPE_AGENT);
    } else {
      if (tid == 0){
        __hip_atomic_store(&slots[bx], bgen, __ATOMIC_RELEASE, __HIP_MEMORY_SCOPE_AGENT);
        while (__hip_atomic_load(gen, __ATOMIC_ACQUIRE, __HIP_MEMORY_SCOPE_AGENT) < bgen)
          __builtin_amdgcn_s_sleep(1);
      }
      __syncthreads();
    }
  };

  // zero h_{-1} (slot 0) for own (layer, columns)
  {
    ushort_t* hz = hbuf + (size_t)layer*2*(B_*H_);
    for (int r2 = tid; r2 < B_*16; r2 += NT){
      int b = r2 >> 4, j = r2 & 15;
      hz[(size_t)b*H_ + jbase + j] = 0;
    }
  }
  gridbar();

  // biases (thread owns column j = tid&15 in pointwise stage)
  float bs4[4];
  {
    const int jc = jbase + (tid & 15);
    #pragma unroll
    for (int g = 0; g < 4; ++g){
      const size_t idx = (size_t)layer*4*H_ + g*H_ + jc;
      bs4[g] = f32in ? (((const float*)bihv)[idx] + ((const float*)bhhv)[idx])
                     : (bs2f(((const ushort_t*)bihv)[idx]) + bs2f(((const ushort_t*)bhhv)[idx]));
    }
  }
  float cpair[2] = {0.f, 0.f};

  const int m0 = mh*32 + l15;
  const size_t wrow = (size_t)(wg*H_ + jbase + l15);

  for (int s = 0; s < T_ + 3; ++s){
    const int t = s - layer;
    if (t >= 0 && t < T_){
      floatx4 acc0 = {0.f,0.f,0.f,0.f}, acc1 = {0.f,0.f,0.f,0.f};

      // ---------- input GEMM ----------
      if (rawf32){
        const float* ww = wihF + (size_t)layer*4*H_*D_ + wrow*D_;
        if (layer == 0){
          const float* xrow = xF + (size_t)t*D_;
          #pragma unroll 4
          for (int kk = 0; kk < 32; ++kk){
            const int ko = kk*32 + q*8;
            short8 bv = cvt8(ww + ko);
            short8 a0 = cvt8(xrow + (size_t)m0*T_*D_ + ko);
            short8 a1 = cvt8(xrow + (size_t)(m0+16)*T_*D_ + ko);
            acc0 = __builtin_amdgcn_mfma_f32_16x16x32_bf16(a0, bv, acc0, 0, 0, 0);
            acc1 = __builtin_amdgcn_mfma_f32_16x16x32_bf16(a1, bv, acc1, 0, 0, 0);
          }
        } else {
          const ushort_t* ib = hbuf + ((size_t)(layer-1)*2 + ((t+1)&1))*(B_*H_);
          #pragma unroll 4
          for (int kk = 0; kk < 32; ++kk){
            const int ko = kk*32 + q*8;
            short8 bv = cvt8(ww + ko);
            short8 a0 = ldb8(ib + (size_t)m0*H_ + ko);
            short8 a1 = ldb8(ib + (size_t)(m0+16)*H_ + ko);
            acc0 = __builtin_amdgcn_mfma_f32_16x16x32_bf16(a0, bv, acc0, 0, 0, 0);
            acc1 = __builtin_amdgcn_mfma_f32_16x16x32_bf16(a1, bv, acc1, 0, 0, 0);
          }
        }
      } else {
        const ushort_t* ww = wihB + (size_t)layer*4*H_*D_ + wrow*D_;
        if (layer == 0){
          if (f32in){
            const float* xrow = xF + (size_t)t*D_;
            #pragma unroll 4
            for (int kk = 0; kk < 32; ++kk){
              const int ko = kk*32 + q*8;
              short8 bv = ldb8(ww + ko);
              short8 a0 = cvt8(xrow + (size_t)m0*T_*D_ + ko);
              short8 a1 = cvt8(xrow + (size_t)(m0+16)*T_*D_ + ko);
              acc0 = __builtin_amdgcn_mfma_f32_16x16x32_bf16(a0, bv, acc0, 0, 0, 0);
              acc1 = __builtin_amdgcn_mfma_f32_16x16x32_bf16(a1, bv, acc1, 0, 0, 0);
            }
          } else {
            const ushort_t* xrow = xB + (size_t)t*D_;
            #pragma unroll 4
            for (int kk = 0; kk < 32; ++kk){
              const int ko = kk*32 + q*8;
              short8 bv = ldb8(ww + ko);
              short8 a0 = ldb8(xrow + (size_t)m0*T_*D_ + ko);
              short8 a1 = ldb8(xrow + (size_t)(m0+16)*T_*D_ + ko);
              acc0 = __builtin_amdgcn_mfma_f32_16x16x32_bf16(a0, bv, acc0, 0, 0, 0);
              acc1 = __builtin_amdgcn_mfma_f32_16x16x32_bf16(a1, bv, acc1, 0, 0, 0);
            }
          }
        } else {
          const ushort_t* ib = hbuf + ((size_t)(layer-1)*2 + ((t+1)&1))*(B_*H_);
          #pragma unroll 4
          for (int kk = 0; kk < 32; ++kk){
            const int ko = kk*32 + q*8;
            short8 bv = ldb8(ww + ko);
            short8 a0 = ldb8(ib + (size_t)m0*H_ + ko);
            short8 a1 = ldb8(ib + (size_t)(m0+16)*H_ + ko);
            acc0 = __builtin_amdgcn_mfma_f32_16x16x32_bf16(a0, bv, acc0, 0, 0, 0);
            acc1 = __builtin_amdgcn_mfma_f32_16x16x32_bf16(a1, bv, acc1, 0, 0, 0);
          }
        }
      }

      // ---------- recurrent GEMM ----------
      const ushort_t* hrd = hbuf + ((size_t)layer*2 + (t&1))*(B_*H_);
      if (rawf32){
        const float* ww = whhF + (size_t)layer*4*H_*H_ + wrow*H_;
        #pragma unroll 4
        for (int kk = 0; kk < 32; ++kk){
          const int ko = kk*32 + q*8;
          short8 bv = cvt8(ww + ko);
          short8 a0 = ldb8(hrd + (size_t)m0*H_ + ko);
          short8 a1 = ldb8(hrd + (size_t)(m0+16)*H_ + ko);
          acc0 = __builtin_amdgcn_mfma_f32_16x16x32_bf16(a0, bv, acc0, 0, 0, 0);
          acc1 = __builtin_amdgcn_mfma_f32_16x16x32_bf16(a1, bv, acc1, 0, 0, 0);
        }
      } else {
        const ushort_t* ww = whhB + (size_t)layer*4*H_*H_ + wrow*H_;
        #pragma unroll 4
        for (int kk = 0; kk < 32; ++kk){
          const int ko = kk*32 + q*8;
          short8 bv = ldb8(ww + ko);
          short8 a0 = ldb8(hrd + (size_t)m0*H_ + ko);
          short8 a1 = ldb8(hrd + (size_t)(m0+16)*H_ + ko);
          acc0 = __builtin_amdgcn_mfma_f32_16x16x32_bf16(a0, bv, acc0, 0, 0, 0);
          acc1 = __builtin_amdgcn_mfma_f32_16x16x32_bf16(a1, bv, acc1, 0, 0, 0);
        }
      }

      // gate exchange (C/D layout: col=lane&15, row=q*4+r)
      #pragma unroll
      for (int r = 0; r < 4; ++r){
        xch[wg][mh*32      + q*4 + r][l15] = acc0[r];
        xch[wg][mh*32 + 16 + q*4 + r][l15] = acc1[r];
      }
      __syncthreads();

      // pointwise cell, fully in registers
      const int j  = tid & 15;
      const int b0 = tid >> 4;
      ushort_t* hwr = hbuf + ((size_t)layer*2 + ((t+1)&1))*(B_*H_);
      #pragma unroll
      for (int p = 0; p < 2; ++p){
        const int b = b0 + p*32;
        float ig = sigf (xch[0][b][j] + bs4[0]);
        float fg = sigf (xch[1][b][j] + bs4[1]);
        float gg = tanh_f(xch[2][b][j] + bs4[2]);
        float og = sigf (xch[3][b][j] + bs4[3]);
        float cn = fg*cpair[p] + ig*gg;
        cpair[p] = cn;
        float h = og*tanh_f(cn);
        hwr[(size_t)b*H_ + jbase + j] = f2bs(h);
        if (layer == 3 && t == T_-1) hlast[(size_t)b*H_ + jbase + j] = h;
      }
    }
    gridbar();
  }

  // ---------- FC epilogue ----------
  if (bx < B_ && tid < O_){
    const int b = bx, o = tid;
    const float* hr = hlast + (size_t)b*H_;
    float acc;
    if (f32in){
      acc = ((const float*)fcbv)[o];
      const float* wr = (const float*)fcwv + (size_t)o*H_;
      for (int k = 0; k < H_; ++k) acc += hr[k] * wr[k];
      ((float*)outv)[(size_t)b*O_ + o] = acc;
    } else {
      acc = bs2f(((const ushort_t*)fcbv)[o]);
      const ushort_t* wr = (const ushort_t*)fcwv + (size_t)o*H_;
      for (int k8 = 0; k8 < H_/8; ++k8){
        short8 w = ldb8(wr + k8*8);
        #pragma unroll
        for (int u = 0; u < 8; ++u) acc += hr[k8*8 + u] * bs2f((ushort_t)w[u]);
      }
      ((ushort_t*)outv)[(size_t)b*O_ + o] = f2bs(acc);
    }
  }
}

extern "C" void kernel_launch(void* const* d_in, const int* in_sizes, int n_in,
                              void* d_out, int out_size, void* d_ws, size_t ws_size,
                              hipStream_t stream){
  char* ws = (char*)d_ws;
  unsigned* bar   = (unsigned*)(ws + WS_BAR);
  unsigned* mode  = (unsigned*)(ws + WS_MODE);
  ushort_t* hbuf  = (ushort_t*)(ws + WS_HBUF);
  float*    hlast = (float*)(ws + WS_HLAST);
  ushort_t* wsWih = (ushort_t*)(ws + WS_WIH);
  ushort_t* wsWhh = (ushort_t*)(ws + WS_WHH);
  const int ws_ok = (ws_size >= WS_NEED) ? 1 : 0;

  sniff_init<<<1, 256, 0, stream>>>((const ushort_t*)d_in[6], bar, mode);
  wconv<<<512, 256, 0, stream>>>((const float*)d_in[1], (const float*)d_in[2],
                                 wsWih, wsWhh, mode, ws_ok);
  lstm_pipe<<<NB, NT, 0, stream>>>(d_in[0], d_in[1], d_in[2], d_in[3], d_in[4],
                                   d_in[5], d_in[6], d_out,
                                   hbuf, hlast, bar, mode, wsWih, wsWhh, ws_ok);
}

// Round 4
// 27808.167 us; speedup vs baseline: 1.6414x; 1.6414x over previous
//
#include <hip/hip_runtime.h>

typedef __attribute__((ext_vector_type(8))) short short8;
typedef __attribute__((ext_vector_type(4))) float floatx4;
typedef unsigned short ushort_t;

#define NB 256
#define NT 512
constexpr int B_ = 64, T_ = 512, D_ = 1024, H_ = 1024, O_ = 256;

// ---- ws layout (bytes) ----
constexpr size_t WS_SLOTS = 0;      // unsigned slots[4][64]: timesteps completed per (layer, slice)
constexpr size_t WS_MODE  = 4096;   // unsigned: 1 = f32 inputs
constexpr size_t WS_HBUF  = 8192;   // bf16 hbuf[4][4][64][1024]  (layer, ring slot t%4, batch, H) = 2 MiB
constexpr size_t WS_NEED  = WS_HBUF + (size_t)4*4*B_*H_*2;

__device__ __forceinline__ float bs2f(ushort_t s){
  union { unsigned u; float f; } v; v.u = ((unsigned)s) << 16; return v.f;
}
__device__ __forceinline__ ushort_t f2bs(float f){
  union { float f; unsigned u; } v; v.f = f;
  unsigned r = (v.u + 0x7fffu + ((v.u >> 16) & 1u)) >> 16;
  return (ushort_t)r;
}
__device__ __forceinline__ float sigf(float x){ return 1.f/(1.f + __expf(-x)); }
__device__ __forceinline__ float tanh_f(float x){ return 1.f - 2.f/(__expf(2.f*x) + 1.f); }
__device__ __forceinline__ short8 ldb8(const ushort_t* p){ return *(const short8*)p; }
__device__ __forceinline__ short8 cvt8v(const float* p){
  floatx4 a = *(const floatx4*)p;
  floatx4 b = *(const floatx4*)(p + 4);
  short8 r;
  #pragma unroll
  for (int j = 0; j < 4; ++j){ r[j] = (short)f2bs(a[j]); r[j+4] = (short)f2bs(b[j]); }
  return r;
}
__device__ __forceinline__ void waitge(unsigned* p, int tgt){
  while ((int)__hip_atomic_load(p, __ATOMIC_RELAXED, __HIP_MEMORY_SCOPE_AGENT) < tgt)
    __builtin_amdgcn_s_sleep(2);
  (void)__hip_atomic_load(p, __ATOMIC_ACQUIRE, __HIP_MEMORY_SCOPE_AGENT);  // L1 inv + ordering
}

// ---- kernel 1: dtype sniff + slot init ----
__global__ void sniff_init(const ushort_t* __restrict__ fcb_u,
                           unsigned* __restrict__ slots, unsigned* __restrict__ mode){
  __shared__ int cnt;
  if (threadIdx.x == 0) cnt = 0;
  __syncthreads();
  slots[threadIdx.x] = 0u;                 // 256 threads, 256 slots
  unsigned u = fcb_u[threadIdx.x];         // first 512B of fcb: safe for both dtypes
  unsigned e = (u >> 7) & 0xFFu;
  if (e >= 0x89u) atomicAdd(&cnt, 1);
  __syncthreads();
  if (threadIdx.x == 0) *mode = (cnt >= 4) ? 1u : 0u;
}

// ---- kernel 2: persistent pipelined LSTM, weights resident in VGPRs ----
// 256 blocks x 512 thr; block = (layer = bx>>6, 16 h-cols). 8 waves = (gate wg, K-half kh).
// Each wave holds its B-frags for Wih & Whh in 128 VGPRs, computes all 4 m-tiles (M=64).
// Sync: per-(layer,slice) progress slots, release/acquire agent scope; 4-deep h ring.
__global__ __launch_bounds__(NT, 2)
void lstm_pipe(const void* __restrict__ xv,   const void* __restrict__ Wihv,
               const void* __restrict__ Whhv, const void* __restrict__ bihv,
               const void* __restrict__ bhhv, const void* __restrict__ fcwv,
               const void* __restrict__ fcbv, void* __restrict__ outv,
               ushort_t* __restrict__ hbuf, unsigned* __restrict__ slots,
               const unsigned* __restrict__ modep)
{
  const int tid  = threadIdx.x;
  const int bx   = blockIdx.x;
  const int lane = tid & 63;
  const int wv   = tid >> 6;
  const int q    = lane >> 4;
  const int l15  = lane & 15;
  const int wg   = wv >> 1;           // gate 0..3
  const int kh   = wv & 1;            // K-half
  const int layer = bx >> 6;
  const int slice = bx & 63;
  const int jbase = slice * 16;

  __shared__ float xch[4][2][64][17];  // [gate][khalf][b][j] + pad

  const unsigned md = *modep;
  const bool f32in  = (md == 1u);
  const float*    xF = (const float*)xv;
  const ushort_t* xB = (const ushort_t*)xv;

  // ---- load this wave's weight B-fragments into registers (once) ----
  short8 wih_r[16], whh_r[16];
  {
    const size_t wrow = (size_t)layer*4*H_ + (size_t)wg*H_ + jbase + l15;
    const size_t koff = (size_t)kh*512 + q*8;
    if (f32in){
      const float* wi = (const float*)Wihv + wrow*D_ + koff;
      const float* wh = (const float*)Whhv + wrow*H_ + koff;
      #pragma unroll
      for (int kk = 0; kk < 16; ++kk){
        wih_r[kk] = cvt8v(wi + kk*32);
        whh_r[kk] = cvt8v(wh + kk*32);
      }
    } else {
      const ushort_t* wi = (const ushort_t*)Wihv + wrow*D_ + koff;
      const ushort_t* wh = (const ushort_t*)Whhv + wrow*H_ + koff;
      #pragma unroll
      for (int kk = 0; kk < 16; ++kk){
        wih_r[kk] = ldb8(wi + kk*32);
        whh_r[kk] = ldb8(wh + kk*32);
      }
    }
  }

  // ---- biases for pointwise (thread owns column j = tid&15) ----
  float bs4[4];
  {
    const int jc = jbase + (tid & 15);
    #pragma unroll
    for (int g = 0; g < 4; ++g){
      const size_t idx = (size_t)layer*4*H_ + g*H_ + jc;
      bs4[g] = f32in ? (((const float*)bihv)[idx] + ((const float*)bhhv)[idx])
                     : (bs2f(((const ushort_t*)bihv)[idx]) + bs2f(((const ushort_t*)bhhv)[idx]));
    }
  }
  float cpair[2] = {0.f, 0.f};

  // ---- zero h_{-1} (ring slot 3) for own slice, publish progress=1 ----
  {
    ushort_t* hz = hbuf + ((size_t)layer*4 + 3)*(B_*H_);
    for (int r = tid; r < B_*16; r += NT){
      int b = r >> 4, j = r & 15;
      hz[(size_t)b*H_ + jbase + j] = 0;
    }
  }
  __syncthreads();
  if (tid == 0)
    __hip_atomic_store(&slots[layer*64 + slice], 1u, __ATOMIC_RELEASE, __HIP_MEMORY_SCOPE_AGENT);

  const size_t akoff = (size_t)kh*512 + q*8;

  for (int t = 0; t < T_; ++t){
    // A) wait prev-layer h_t; back-pressure on ring reuse (2 steps of slack)
    if (layer > 0 && tid < 64)               waitge(&slots[(layer-1)*64 + tid], t + 2);
    if (layer < 3 && t >= 3 && tid >= 64 && tid < 128)
                                             waitge(&slots[(layer+1)*64 + (tid-64)], t - 2);
    __syncthreads();

    floatx4 acc[4];
    #pragma unroll
    for (int mt = 0; mt < 4; ++mt) acc[mt] = floatx4{0.f,0.f,0.f,0.f};

    // B) input GEMM (uses wih_r)
    if (layer == 0){
      if (f32in){
        const float* xp = xF + ((size_t)l15*T_ + t)*D_ + akoff;
        #pragma unroll
        for (int kk = 0; kk < 16; ++kk){
          short8 a0 = cvt8v(xp + kk*32);
          short8 a1 = cvt8v(xp + (size_t)16*T_*D_ + kk*32);
          short8 a2 = cvt8v(xp + (size_t)32*T_*D_ + kk*32);
          short8 a3 = cvt8v(xp + (size_t)48*T_*D_ + kk*32);
          acc[0] = __builtin_amdgcn_mfma_f32_16x16x32_bf16(a0, wih_r[kk], acc[0], 0,0,0);
          acc[1] = __builtin_amdgcn_mfma_f32_16x16x32_bf16(a1, wih_r[kk], acc[1], 0,0,0);
          acc[2] = __builtin_amdgcn_mfma_f32_16x16x32_bf16(a2, wih_r[kk], acc[2], 0,0,0);
          acc[3] = __builtin_amdgcn_mfma_f32_16x16x32_bf16(a3, wih_r[kk], acc[3], 0,0,0);
        }
      } else {
        const ushort_t* xp = xB + ((size_t)l15*T_ + t)*D_ + akoff;
        #pragma unroll
        for (int kk = 0; kk < 16; ++kk){
          short8 a0 = ldb8(xp + kk*32);
          short8 a1 = ldb8(xp + (size_t)16*T_*D_ + kk*32);
          short8 a2 = ldb8(xp + (size_t)32*T_*D_ + kk*32);
          short8 a3 = ldb8(xp + (size_t)48*T_*D_ + kk*32);
          acc[0] = __builtin_amdgcn_mfma_f32_16x16x32_bf16(a0, wih_r[kk], acc[0], 0,0,0);
          acc[1] = __builtin_amdgcn_mfma_f32_16x16x32_bf16(a1, wih_r[kk], acc[1], 0,0,0);
          acc[2] = __builtin_amdgcn_mfma_f32_16x16x32_bf16(a2, wih_r[kk], acc[2], 0,0,0);
          acc[3] = __builtin_amdgcn_mfma_f32_16x16x32_bf16(a3, wih_r[kk], acc[3], 0,0,0);
        }
      }
    } else {
      const ushort_t* ip = hbuf + ((size_t)(layer-1)*4 + (t&3))*(B_*H_) + (size_t)l15*H_ + akoff;
      #pragma unroll
      for (int kk = 0; kk < 16; ++kk){
        short8 a0 = ldb8(ip + kk*32);
        short8 a1 = ldb8(ip + (size_t)16*H_ + kk*32);
        short8 a2 = ldb8(ip + (size_t)32*H_ + kk*32);
        short8 a3 = ldb8(ip + (size_t)48*H_ + kk*32);
        acc[0] = __builtin_amdgcn_mfma_f32_16x16x32_bf16(a0, wih_r[kk], acc[0], 0,0,0);
        acc[1] = __builtin_amdgcn_mfma_f32_16x16x32_bf16(a1, wih_r[kk], acc[1], 0,0,0);
        acc[2] = __builtin_amdgcn_mfma_f32_16x16x32_bf16(a2, wih_r[kk], acc[2], 0,0,0);
        acc[3] = __builtin_amdgcn_mfma_f32_16x16x32_bf16(a3, wih_r[kk], acc[3], 0,0,0);
      }
    }

    // C) wait own-layer h_{t-1} (also guarantees siblings done reading ring slot t%4)
    if (tid < 64) waitge(&slots[layer*64 + tid], t + 1);
    __syncthreads();

    // D) recurrent GEMM (uses whh_r) from ring slot (t-1)%4
    {
      const ushort_t* hp = hbuf + ((size_t)layer*4 + ((t+3)&3))*(B_*H_) + (size_t)l15*H_ + akoff;
      #pragma unroll
      for (int kk = 0; kk < 16; ++kk){
        short8 a0 = ldb8(hp + kk*32);
        short8 a1 = ldb8(hp + (size_t)16*H_ + kk*32);
        short8 a2 = ldb8(hp + (size_t)32*H_ + kk*32);
        short8 a3 = ldb8(hp + (size_t)48*H_ + kk*32);
        acc[0] = __builtin_amdgcn_mfma_f32_16x16x32_bf16(a0, whh_r[kk], acc[0], 0,0,0);
        acc[1] = __builtin_amdgcn_mfma_f32_16x16x32_bf16(a1, whh_r[kk], acc[1], 0,0,0);
        acc[2] = __builtin_amdgcn_mfma_f32_16x16x32_bf16(a2, whh_r[kk], acc[2], 0,0,0);
        acc[3] = __builtin_amdgcn_mfma_f32_16x16x32_bf16(a3, whh_r[kk], acc[3], 0,0,0);
      }
    }

    // E) exchange partial gates (C/D layout: col=lane&15, row=q*4+r)
    #pragma unroll
    for (int mt = 0; mt < 4; ++mt){
      #pragma unroll
      for (int r = 0; r < 4; ++r)
        xch[wg][kh][mt*16 + q*4 + r][l15] = acc[mt][r];
    }
    __syncthreads();

    // F) pointwise cell (thread owns j = tid&15, b = tid>>4 and +32), write h_t
    {
      const int j  = tid & 15;
      const int b0 = tid >> 4;
      ushort_t* hw = hbuf + ((size_t)layer*4 + (t&3))*(B_*H_);
      #pragma unroll
      for (int p = 0; p < 2; ++p){
        const int b = b0 + p*32;
        float ig = sigf  (xch[0][0][b][j] + xch[0][1][b][j] + bs4[0]);
        float fg = sigf  (xch[1][0][b][j] + xch[1][1][b][j] + bs4[1]);
        float gg = tanh_f(xch[2][0][b][j] + xch[2][1][b][j] + bs4[2]);
        float og = sigf  (xch[3][0][b][j] + xch[3][1][b][j] + bs4[3]);
        float cn = fg*cpair[p] + ig*gg;
        cpair[p] = cn;
        hw[(size_t)b*H_ + jbase + j] = f2bs(og*tanh_f(cn));
      }
    }
    __syncthreads();
    if (tid == 0)
      __hip_atomic_store(&slots[layer*64 + slice], (unsigned)(t + 2),
                         __ATOMIC_RELEASE, __HIP_MEMORY_SCOPE_AGENT);
  }

  // ---- FC epilogue: blocks 0..63 -> batch row; threads 0..255 -> output col ----
  if (bx < B_){
    if (tid < 64) waitge(&slots[3*64 + tid], T_ + 1);
    __syncthreads();
    if (tid < O_){
      const int b = bx, o = tid;
      const ushort_t* hr = hbuf + (((size_t)3*4 + ((T_-1)&3))*B_ + b)*H_;   // layer 3, slot 3
      if (f32in){
        float acc = ((const float*)fcbv)[o];
        const float* wr = (const float*)fcwv + (size_t)o*H_;
        for (int k8 = 0; k8 < H_/8; ++k8){
          short8 h8 = ldb8(hr + k8*8);
          #pragma unroll
          for (int u = 0; u < 8; ++u) acc += bs2f((ushort_t)h8[u]) * wr[k8*8 + u];
        }
        ((float*)outv)[(size_t)b*O_ + o] = acc;
      } else {
        float acc = bs2f(((const ushort_t*)fcbv)[o]);
        const ushort_t* wr = (const ushort_t*)fcwv + (size_t)o*H_;
        for (int k8 = 0; k8 < H_/8; ++k8){
          short8 h8 = ldb8(hr + k8*8);
          short8 w8 = ldb8(wr + k8*8);
          #pragma unroll
          for (int u = 0; u < 8; ++u) acc += bs2f((ushort_t)h8[u]) * bs2f((ushort_t)w8[u]);
        }
        ((ushort_t*)outv)[(size_t)b*O_ + o] = f2bs(acc);
      }
    }
  }
}

extern "C" void kernel_launch(void* const* d_in, const int* in_sizes, int n_in,
                              void* d_out, int out_size, void* d_ws, size_t ws_size,
                              hipStream_t stream){
  char* ws = (char*)d_ws;
  unsigned* slots = (unsigned*)(ws + WS_SLOTS);
  unsigned* mode  = (unsigned*)(ws + WS_MODE);
  ushort_t* hbuf  = (ushort_t*)(ws + WS_HBUF);

  sniff_init<<<1, 256, 0, stream>>>((const ushort_t*)d_in[6], slots, mode);
  lstm_pipe<<<NB, NT, 0, stream>>>(d_in[0], d_in[1], d_in[2], d_in[3], d_in[4],
                                   d_in[5], d_in[6], d_out, hbuf, slots, mode);
}